// Round 3
// baseline (416.931 us; speedup 1.0000x reference)
//
#include <hip/hip_runtime.h>
#include <cstdint>
#include <cstddef>

// Problem constants
#define B_N 65536
#define D_N 256
#define W_N 1024

typedef __bf16 bf16x8 __attribute__((ext_vector_type(8)));
typedef float f32x4 __attribute__((ext_vector_type(4)));
typedef float f32x16 __attribute__((ext_vector_type(16)));
typedef unsigned short u16x8 __attribute__((ext_vector_type(8)));
typedef unsigned short u16x4 __attribute__((ext_vector_type(4)));

__device__ __forceinline__ unsigned short f2bf(float f) {
  // round-to-nearest-even f32 -> bf16 (no NaN in this problem)
  unsigned u = __float_as_uint(f);
  u += 0x7fffu + ((u >> 16) & 1u);
  return (unsigned short)(u >> 16);
}

// ---------------------------------------------------------------------------
// Prep: cast W1 [1024x256] + W2 [256x1024] to bf16, and M[j] = sum_i W1[j,i]*W2[i,j]
// Fully coalesced: 64 blocks handle 64x64 tiles; W2 tile transposed via LDS so
// the M-reduction reads both operands coalesced. M zeroed by memsetAsync.
// ---------------------------------------------------------------------------
__global__ __launch_bounds__(256) void prep_kernel(
    const float* __restrict__ W1, const float* __restrict__ W2,
    unsigned short* __restrict__ W1b, unsigned short* __restrict__ W2b,
    float* __restrict__ M) {
  __shared__ float w2t[64][65]; // w2t[j][i] = W2[i0+i][j0+j]
  const int jt = blockIdx.x >> 2;  // 0..15
  const int it = blockIdx.x & 3;   // 0..3
  const int j0 = jt * 64, i0 = it * 64;
  const int t = threadIdx.x;
  {
    const int i = t >> 2, jq = t & 3; // row i0+i, j quarter
    const float* p2 = W2 + (size_t)(i0 + i) * W_N + j0 + jq * 16;
    unsigned short* q2 = W2b + (size_t)(i0 + i) * W_N + j0 + jq * 16;
    #pragma unroll
    for (int g = 0; g < 4; ++g) {
      f32x4 v = *(const f32x4*)(p2 + g * 4);
      u16x4 c; c[0] = f2bf(v[0]); c[1] = f2bf(v[1]); c[2] = f2bf(v[2]); c[3] = f2bf(v[3]);
      *(u16x4*)(q2 + g * 4) = c;
      w2t[jq * 16 + g * 4 + 0][i] = v[0];
      w2t[jq * 16 + g * 4 + 1][i] = v[1];
      w2t[jq * 16 + g * 4 + 2][i] = v[2];
      w2t[jq * 16 + g * 4 + 3][i] = v[3];
    }
  }
  __syncthreads();
  {
    const int j = t >> 2, iq = t & 3; // row j0+j, i quarter
    const float* p1 = W1 + (size_t)(j0 + j) * D_N + i0 + iq * 16;
    unsigned short* q1 = W1b + (size_t)(j0 + j) * D_N + i0 + iq * 16;
    float acc = 0.f;
    #pragma unroll
    for (int g = 0; g < 4; ++g) {
      f32x4 v = *(const f32x4*)(p1 + g * 4);
      u16x4 c; c[0] = f2bf(v[0]); c[1] = f2bf(v[1]); c[2] = f2bf(v[2]); c[3] = f2bf(v[3]);
      *(u16x4*)(q1 + g * 4) = c;
      acc += v[0] * w2t[j][iq * 16 + g * 4 + 0];
      acc += v[1] * w2t[j][iq * 16 + g * 4 + 1];
      acc += v[2] * w2t[j][iq * 16 + g * 4 + 2];
      acc += v[3] * w2t[j][iq * 16 + g * 4 + 3];
    }
    acc += __shfl_xor(acc, 1);
    acc += __shfl_xor(acc, 2);
    if (iq == 0) atomicAdd(M + j0 + j, acc);
  }
}

// ---------------------------------------------------------------------------
// Fused flow kernel, MFMA 32x32x16 bf16.  BM=64 rows/block, 512 thr = 8 waves
// arranged 2 row-groups (rg) x 4 col-groups (cg); wave tile = 32 rows x 64 cols
// per chunk (2 col-tiles of 32).  W chunked 4 x 256.
// A/B frag (32x32x16): elem[m=lane&31][k = ks*16 + (lane>>5)*8 + i], 8 bf16/lane.
// C/D: col=lane&31, row=(reg&3)+8*(reg>>2)+4*(lane>>5)   [HW-verified m74/m101]
// LDS blocked layout for z/h [64 rows x 256 k]:
//   slot(m,k) = (k>>4)*128 + (m>>5)*64 + ((k>>3)&1)*32 + (m&31), byte=(k&7)*2
//   => A-frag read (ks, rg) = 16B at base + lane*16 (contiguous 1 KB/wave).
// ---------------------------------------------------------------------------
__global__ __launch_bounds__(512, 2) void flow_kernel(
    const float* __restrict__ z, const float* __restrict__ b1,
    const unsigned short* __restrict__ W1b, const unsigned short* __restrict__ W2b,
    const float* __restrict__ M, float* __restrict__ dz, float* __restrict__ tr) {
  __shared__ __align__(16) unsigned short z_sh[16 * 128 * 8]; // 32 KB
  __shared__ __align__(16) unsigned short h_sh[16 * 128 * 8]; // 32 KB

  const int tid = threadIdx.x;
  const int wave = tid >> 6; // 0..7
  const int lane = tid & 63;
  const int rg = wave >> 2;  // row-group 0/1 (rows rg*32..+32)
  const int cg = wave & 3;   // col-group 0..3 (cols cg*64..+64 of chunk)
  const int l31 = lane & 31;
  const int lh = lane >> 5;  // 0/1
  const int row0 = blockIdx.x * 64;

  // ---- stage z tile [64 x 256] f32 -> bf16 blocked layout ----
  #pragma unroll
  for (int it = 0; it < 4; ++it) {
    int id = it * 512 + tid; // 0..2047 = 64 rows x 32 octets
    int m = id >> 5;
    int o = id & 31; // octet: k = o*8..o*8+7
    const float* gp = z + (size_t)(row0 + m) * D_N + o * 8;
    f32x4 a = *(const f32x4*)gp;
    f32x4 b = *(const f32x4*)(gp + 4);
    u16x8 v;
    v[0] = f2bf(a[0]); v[1] = f2bf(a[1]); v[2] = f2bf(a[2]); v[3] = f2bf(a[3]);
    v[4] = f2bf(b[0]); v[5] = f2bf(b[1]); v[6] = f2bf(b[2]); v[7] = f2bf(b[3]);
    int slot = (o >> 1) * 128 + (m >> 5) * 64 + (o & 1) * 32 + (m & 31);
    *(u16x8*)(z_sh + slot * 8) = v;
  }
  __syncthreads();

  f32x16 acc2[2]; // dz acc: [tn], cols cg*64 + tn*32 + l31
  #pragma unroll
  for (int tn = 0; tn < 2; ++tn)
    #pragma unroll
    for (int r = 0; r < 16; ++r) acc2[tn][r] = 0.f;
  float trp[16]; // per-reg trace partial; row = rg*32 + (reg&3)+8*(reg>>2)+4*lh
  #pragma unroll
  for (int r = 0; r < 16; ++r) trp[r] = 0.f;

  #pragma unroll 1
  for (int c = 0; c < 4; ++c) {
    const int j0 = c * 256;

    // ---- GEMM1: pre[32rows x 64cols] = z @ W1^T, K = 256 (16 ks) ----
    f32x16 acc1[2];
    #pragma unroll
    for (int tn = 0; tn < 2; ++tn)
      #pragma unroll
      for (int r = 0; r < 16; ++r) acc1[tn][r] = 0.f;

    #pragma unroll
    for (int ks = 0; ks < 16; ++ks) {
      bf16x8 afr = *(const bf16x8*)(z_sh + (ks * 128 + rg * 64 + lane) * 8);
      bf16x8 bfr0 = *(const bf16x8*)(W1b +
          (size_t)(j0 + cg * 64 + l31) * D_N + ks * 16 + lh * 8);
      bf16x8 bfr1 = *(const bf16x8*)(W1b +
          (size_t)(j0 + cg * 64 + 32 + l31) * D_N + ks * 16 + lh * 8);
      acc1[0] = __builtin_amdgcn_mfma_f32_32x32x16_bf16(afr, bfr0, acc1[0], 0, 0, 0);
      acc1[1] = __builtin_amdgcn_mfma_f32_32x32x16_bf16(afr, bfr1, acc1[1], 0, 0, 0);
    }

    __syncthreads(); // all waves done reading h_sh (previous chunk's GEMM2)

    // ---- epilogue: softplus -> h_sh, sigmoid*M -> trace partials ----
    #pragma unroll
    for (int tn = 0; tn < 2; ++tn) {
      const int jl = cg * 64 + tn * 32 + l31; // chunk-local col 0..255
      const int jg = j0 + jl;
      const float b1v = b1[jg];
      const float Mv = M[jg];
      const int sbase = (jl >> 4) * 128 + rg * 64 + ((jl >> 3) & 1) * 32;
      const int byte_lo = jl & 7;
      #pragma unroll
      for (int reg = 0; reg < 16; ++reg) {
        const int rowl = (reg & 3) + 8 * (reg >> 2) + 4 * lh; // 0..31
        float x = acc1[tn][reg] + b1v;
        float e = __expf(-fabsf(x));
        float inv = __builtin_amdgcn_rcpf(1.0f + e);
        float sig = (x >= 0.f) ? inv : (1.0f - inv);
        float sp = fmaxf(x, 0.f) + __logf(1.0f + e);
        trp[reg] += sig * Mv;
        h_sh[(sbase + rowl) * 8 + byte_lo] = f2bf(sp);
      }
    }
    __syncthreads(); // h_sh ready

    // ---- GEMM2: dz += h @ W2^T over this chunk (16 ks) ----
    #pragma unroll
    for (int ks = 0; ks < 16; ++ks) {
      bf16x8 afr = *(const bf16x8*)(h_sh + (ks * 128 + rg * 64 + lane) * 8);
      bf16x8 bfr0 = *(const bf16x8*)(W2b +
          (size_t)(cg * 64 + l31) * W_N + j0 + ks * 16 + lh * 8);
      bf16x8 bfr1 = *(const bf16x8*)(W2b +
          (size_t)(cg * 64 + 32 + l31) * W_N + j0 + ks * 16 + lh * 8);
      acc2[0] = __builtin_amdgcn_mfma_f32_32x32x16_bf16(afr, bfr0, acc2[0], 0, 0, 0);
      acc2[1] = __builtin_amdgcn_mfma_f32_32x32x16_bf16(afr, bfr1, acc2[1], 0, 0, 0);
    }
  }

  // ---- store dz ----
  #pragma unroll
  for (int tn = 0; tn < 2; ++tn)
    #pragma unroll
    for (int reg = 0; reg < 16; ++reg) {
      const int rowl = (reg & 3) + 8 * (reg >> 2) + 4 * lh;
      dz[(size_t)(row0 + rg * 32 + rowl) * D_N + cg * 64 + tn * 32 + l31] =
          acc2[tn][reg];
    }

  // ---- trace: reduce 32 cols per lane-half, cross-wave via LDS ----
  float* tr_sh = (float*)z_sh; // z_sh dead after last GEMM1
  __syncthreads();
  if (tid < 64) tr_sh[tid] = 0.f;
  __syncthreads();
  #pragma unroll
  for (int reg = 0; reg < 16; ++reg) {
    float v = trp[reg];
    v += __shfl_xor(v, 1);
    v += __shfl_xor(v, 2);
    v += __shfl_xor(v, 4);
    v += __shfl_xor(v, 8);
    v += __shfl_xor(v, 16);
    if (l31 == 0)
      atomicAdd(tr_sh + rg * 32 + (reg & 3) + 8 * (reg >> 2) + 4 * lh, v);
  }
  __syncthreads();
  if (tid < 64) tr[row0 + tid] = -tr_sh[tid];
}

extern "C" void kernel_launch(void* const* d_in, const int* in_sizes, int n_in,
                              void* d_out, int out_size, void* d_ws, size_t ws_size,
                              hipStream_t stream) {
  (void)in_sizes; (void)n_in; (void)out_size; (void)ws_size;
  // inputs: t[1], z[B,D], W1[W,D], b1[W], W2[D,W]  (all f32)
  const float* z  = (const float*)d_in[1];
  const float* W1 = (const float*)d_in[2];
  const float* b1 = (const float*)d_in[3];
  const float* W2 = (const float*)d_in[4];
  float* dz = (float*)d_out;          // [B, D]
  float* tr = dz + (size_t)B_N * D_N; // [B]

  unsigned short* W1b = (unsigned short*)d_ws;   // 512 KB
  unsigned short* W2b = W1b + (size_t)W_N * D_N; // 512 KB
  float* M = (float*)(W2b + (size_t)W_N * D_N);  // 4 KB

  hipMemsetAsync(M, 0, W_N * sizeof(float), stream);
  prep_kernel<<<dim3(64), dim3(256), 0, stream>>>(W1, W2, W1b, W2b, M);
  flow_kernel<<<dim3(B_N / 64), dim3(512), 0, stream>>>(z, b1, W1b, W2b, M, dz, tr);
}

// Round 4
// 382.751 us; speedup vs baseline: 1.0893x; 1.0893x over previous
//
#include <hip/hip_runtime.h>
#include <cstdint>
#include <cstddef>

// Problem constants
#define B_N 65536
#define D_N 256
#define W_N 1024

typedef __bf16 bf16x8 __attribute__((ext_vector_type(8)));
typedef float f32x4 __attribute__((ext_vector_type(4)));
typedef unsigned short u16x8 __attribute__((ext_vector_type(8)));

__device__ __forceinline__ unsigned short f2bf(float f) {
  // round-to-nearest-even f32 -> bf16 (no NaN in this problem)
  unsigned u = __float_as_uint(f);
  u += 0x7fffu + ((u >> 16) & 1u);
  return (unsigned short)(u >> 16);
}

// LDS bank swizzle for the z/h blocked layouts: permutes the low 3 bits of the
// 16B-slot index by higher bits so that staging writes (which sweep slot bits
// [5:4] and [10:8] at fixed low bits -> 8-way conflict unswizzled) spread over
// all 8 bank groups.  Pure function of slot => writers/readers stay coherent;
// fragment reads sweep 64 consecutive slots => still a bijection (conflict-free).
__device__ __forceinline__ int swz(int slot) {
  return slot ^ ((slot >> 4) & 7) ^ ((slot >> 8) & 7);
}

// ---------------------------------------------------------------------------
// Weight swizzle: store W1/W2 as bf16 B-fragment "lines" (1 KB each, one per
// (16-col tile nt, 32-k tile ks)).  Line content: lane = q*16 + l15 holds
// W[nt*16 + l15][ks*32 + q*8 + i], i=0..7  == exactly the MFMA 16x16x32 B-frag.
// GEMM B-loads then read line*1024 + lane*16: one coalesced transaction.
// W1: 1024 rows x 256 k -> 64 nt x 8 ks = 512 lines.
// W2: 256 rows x 1024 k -> 16 nt x 32 ks = 512 lines.
// Grid 256 blocks x 256 thr (4 waves); wave w of block b handles line b*4+w.
// ---------------------------------------------------------------------------
__global__ __launch_bounds__(256) void swz_kernel(
    const float* __restrict__ W1, const float* __restrict__ W2,
    unsigned short* __restrict__ W1s, unsigned short* __restrict__ W2s) {
  const int wv = blockIdx.x * 4 + (threadIdx.x >> 6); // 0..1023
  const int lane = threadIdx.x & 63;
  const int l15 = lane & 15, q = lane >> 4;
  if (wv < 512) { // W1 line: nt = wv>>3, ks = wv&7
    const int nt = wv >> 3, ks = wv & 7;
    const float* p = W1 + (size_t)(nt * 16 + l15) * D_N + ks * 32 + q * 8;
    f32x4 a = *(const f32x4*)p;
    f32x4 b = *(const f32x4*)(p + 4);
    u16x8 v;
    v[0] = f2bf(a[0]); v[1] = f2bf(a[1]); v[2] = f2bf(a[2]); v[3] = f2bf(a[3]);
    v[4] = f2bf(b[0]); v[5] = f2bf(b[1]); v[6] = f2bf(b[2]); v[7] = f2bf(b[3]);
    *(u16x8*)(W1s + wv * 512 + lane * 8) = v;
  } else {          // W2 line: w = wv-512, nt = w>>5, ks = w&31
    const int w = wv - 512;
    const int nt = w >> 5, ks = w & 31;
    const float* p = W2 + (size_t)(nt * 16 + l15) * W_N + ks * 32 + q * 8;
    f32x4 a = *(const f32x4*)p;
    f32x4 b = *(const f32x4*)(p + 4);
    u16x8 v;
    v[0] = f2bf(a[0]); v[1] = f2bf(a[1]); v[2] = f2bf(a[2]); v[3] = f2bf(a[3]);
    v[4] = f2bf(b[0]); v[5] = f2bf(b[1]); v[6] = f2bf(b[2]); v[7] = f2bf(b[3]);
    *(u16x8*)(W2s + w * 512 + lane * 8) = v;
  }
}

// M[j] = sum_i W1[j,i] * W2[i,j].  Grid 16 x 256 thr; 4 threads per j.
__global__ __launch_bounds__(256) void m_kernel(
    const float* __restrict__ W1, const float* __restrict__ W2,
    float* __restrict__ M) {
  const int t = threadIdx.x;
  const int j = blockIdx.x * 64 + (t >> 2);
  const int iq = t & 3;
  float s = 0.f;
  #pragma unroll 8
  for (int i = iq * 64; i < iq * 64 + 64; ++i)
    s += W1[(size_t)j * D_N + i] * W2[(size_t)i * W_N + j];
  s += __shfl_xor(s, 1);
  s += __shfl_xor(s, 2);
  if (iq == 0) M[j] = s;
}

// ---------------------------------------------------------------------------
// Fused flow kernel (r2 structure). BM=64 rows/block, 512 thr = 8 waves, each
// wave owns a 64x32 output strip per chunk (tn in {0,1}).  W chunked 4x256.
// LDS: z and h in fragment-linear blocked bf16 layout (+ bank swizzle):
//   element (m,k) -> 16B slot swz(((k/32)*4 + m/16)*64 + ((k%32)/8)*16 + (m%16)),
//   ushort within slot = k%8.  A-frag (ks,tm) = 64 consecutive slots.
// MFMA 16x16x32 bf16: A[m=lane&15][k=(lane>>4)*8+j]; C row=(lane>>4)*4+reg, col=lane&15.
// B-frags come from the pre-swizzled weight lines: fully coalesced 16B/lane.
// ---------------------------------------------------------------------------
__global__ __launch_bounds__(512, 4) void flow_kernel(
    const float* __restrict__ z, const float* __restrict__ b1,
    const unsigned short* __restrict__ W1s, const unsigned short* __restrict__ W2s,
    const float* __restrict__ M, float* __restrict__ dz, float* __restrict__ tr) {
  __shared__ __align__(16) unsigned short z_sh[64 * 256]; // 32 KB
  __shared__ __align__(16) unsigned short h_sh[64 * 256]; // 32 KB

  const int tid = threadIdx.x;
  const int wave = tid >> 6;   // 0..7
  const int lane = tid & 63;
  const int l15 = lane & 15;
  const int q = lane >> 4;     // quad 0..3
  const int row0 = blockIdx.x * 64;
  const int colw = wave * 32;  // wave's column strip within the 256-chunk

  // ---- stage z tile [64 x 256] f32 -> bf16 blocked+swizzled layout ----
  #pragma unroll
  for (int it = 0; it < 4; ++it) {
    int id = it * 512 + tid;
    int m = id >> 5;  // row 0..63
    int o = id & 31;  // octet of 8 floats
    const float* gp = z + (size_t)(row0 + m) * D_N + o * 8;
    f32x4 a = *(const f32x4*)gp;
    f32x4 b = *(const f32x4*)(gp + 4);
    u16x8 v;
    v[0] = f2bf(a[0]); v[1] = f2bf(a[1]); v[2] = f2bf(a[2]); v[3] = f2bf(a[3]);
    v[4] = f2bf(b[0]); v[5] = f2bf(b[1]); v[6] = f2bf(b[2]); v[7] = f2bf(b[3]);
    int slot = swz(((o >> 2) * 4 + (m >> 4)) * 64 + (o & 3) * 16 + (m & 15));
    *(u16x8*)(z_sh + slot * 8) = v;
  }
  __syncthreads();

  f32x4 acc2[4][2]; // dz accumulator: [tm][tn], cols = colw + tn*16 + l15
  #pragma unroll
  for (int a = 0; a < 4; ++a)
    #pragma unroll
    for (int b = 0; b < 2; ++b)
      acc2[a][b] = (f32x4){0.f, 0.f, 0.f, 0.f};
  float trp[4][4]; // trace partial per (tm, reg): row = tm*16 + q*4 + r
  #pragma unroll
  for (int a = 0; a < 4; ++a)
    #pragma unroll
    for (int r = 0; r < 4; ++r) trp[a][r] = 0.f;

  #pragma unroll 1
  for (int c = 0; c < 4; ++c) {
    const int j0 = c * 256;
    const int nt1 = (j0 + colw) >> 4; // W1 col-tile base for this wave

    // ---- GEMM1: pre[64 x 32strip] = z_tile @ W1^T, K = 256 ----
    f32x4 acc1[4][2];
    #pragma unroll
    for (int a = 0; a < 4; ++a)
      #pragma unroll
      for (int b = 0; b < 2; ++b)
        acc1[a][b] = (f32x4){0.f, 0.f, 0.f, 0.f};

    #pragma unroll
    for (int ks = 0; ks < 8; ++ks) {
      bf16x8 afr[4];
      #pragma unroll
      for (int tm = 0; tm < 4; ++tm)
        afr[tm] = *(const bf16x8*)(z_sh + swz((ks * 4 + tm) * 64 + lane) * 8);
      bf16x8 bfr[2];
      #pragma unroll
      for (int tn = 0; tn < 2; ++tn)
        bfr[tn] = *(const bf16x8*)(W1s + ((nt1 + tn) * 8 + ks) * 512 + lane * 8);
      #pragma unroll
      for (int tm = 0; tm < 4; ++tm)
        #pragma unroll
        for (int tn = 0; tn < 2; ++tn)
          acc1[tm][tn] = __builtin_amdgcn_mfma_f32_16x16x32_bf16(
              afr[tm], bfr[tn], acc1[tm][tn], 0, 0, 0);
    }

    __syncthreads(); // all waves done reading h_sh from previous chunk's GEMM2

    // ---- epilogue: softplus -> h_sh (blocked+swizzled), sigmoid*M -> trace ----
    #pragma unroll
    for (int tn = 0; tn < 2; ++tn) {
      const int jl = colw + tn * 16 + l15; // chunk-local j, 0..255
      const int jg = j0 + jl;
      const float b1v = b1[jg];
      const float Mv = M[jg];
      const int sbase = ((jl >> 5) * 4) * 64 + ((jl >> 3) & 3) * 16;
      const int elem_lo = (jl & 7);
      #pragma unroll
      for (int tm = 0; tm < 4; ++tm) {
        #pragma unroll
        for (int r = 0; r < 4; ++r) {
          float x = acc1[tm][tn][r] + b1v;
          float e = __expf(-fabsf(x));
          float inv = __builtin_amdgcn_rcpf(1.0f + e);
          float sig = (x >= 0.f) ? inv : (1.0f - inv);
          float sp = fmaxf(x, 0.f) + __logf(1.0f + e);
          trp[tm][r] += sig * Mv;
          int slot = swz(sbase + tm * 64 + (q * 4 + r)); // row = tm*16 + q*4 + r
          h_sh[slot * 8 + elem_lo] = f2bf(sp);
        }
      }
    }
    __syncthreads(); // h_sh ready

    // ---- GEMM2: dz += h_chunk[64 x 256] @ W2[:, j0+..]^T, K = 256 ----
    const int nt2 = colw >> 4; // W2 row-tile base (output cols) for this wave
    #pragma unroll
    for (int ks = 0; ks < 8; ++ks) {
      bf16x8 afr[4];
      #pragma unroll
      for (int tm = 0; tm < 4; ++tm)
        afr[tm] = *(const bf16x8*)(h_sh + swz((ks * 4 + tm) * 64 + lane) * 8);
      bf16x8 bfr[2];
      #pragma unroll
      for (int tn = 0; tn < 2; ++tn)
        bfr[tn] = *(const bf16x8*)(W2s +
            ((nt2 + tn) * 32 + (c * 8 + ks)) * 512 + lane * 8);
      #pragma unroll
      for (int tm = 0; tm < 4; ++tm)
        #pragma unroll
        for (int tn = 0; tn < 2; ++tn)
          acc2[tm][tn] = __builtin_amdgcn_mfma_f32_16x16x32_bf16(
              afr[tm], bfr[tn], acc2[tm][tn], 0, 0, 0);
    }
  }

  // ---- store dz: out[(row0 + tm*16 + q*4 + r) * 256 + colw + tn*16 + l15] ----
  #pragma unroll
  for (int tm = 0; tm < 4; ++tm)
    #pragma unroll
    for (int tn = 0; tn < 2; ++tn)
      #pragma unroll
      for (int r = 0; r < 4; ++r)
        dz[(size_t)(row0 + tm * 16 + q * 4 + r) * D_N + colw + tn * 16 + l15] =
            acc2[tm][tn][r];

  // ---- trace: reduce 16 lanes per quad, then cross-wave via LDS (reuse z_sh) ----
  float* tr_sh = (float*)z_sh; // z_sh dead after last GEMM1
  __syncthreads();             // everyone past last GEMM1/GEMM2
  if (tid < 64) tr_sh[tid] = 0.f;
  __syncthreads();
  #pragma unroll
  for (int tm = 0; tm < 4; ++tm) {
    #pragma unroll
    for (int r = 0; r < 4; ++r) {
      float v = trp[tm][r];
      v += __shfl_xor(v, 1);
      v += __shfl_xor(v, 2);
      v += __shfl_xor(v, 4);
      v += __shfl_xor(v, 8);
      if (l15 == 0) atomicAdd(tr_sh + tm * 16 + q * 4 + r, v);
    }
  }
  __syncthreads();
  if (tid < 64) tr[row0 + tid] = -tr_sh[tid];
}

extern "C" void kernel_launch(void* const* d_in, const int* in_sizes, int n_in,
                              void* d_out, int out_size, void* d_ws, size_t ws_size,
                              hipStream_t stream) {
  (void)in_sizes; (void)n_in; (void)out_size; (void)ws_size;
  // inputs: t[1], z[B,D], W1[W,D], b1[W], W2[D,W]  (all f32)
  const float* z  = (const float*)d_in[1];
  const float* W1 = (const float*)d_in[2];
  const float* b1 = (const float*)d_in[3];
  const float* W2 = (const float*)d_in[4];
  float* dz = (float*)d_out;          // [B, D]
  float* tr = dz + (size_t)B_N * D_N; // [B]

  unsigned short* W1s = (unsigned short*)d_ws;   // 512 KB (swizzled B-frag lines)
  unsigned short* W2s = W1s + (size_t)W_N * D_N; // 512 KB
  float* M = (float*)(W2s + (size_t)W_N * D_N);  // 4 KB

  m_kernel<<<dim3(16), dim3(256), 0, stream>>>(W1, W2, M);
  swz_kernel<<<dim3(256), dim3(256), 0, stream>>>(W1, W2, W1s, W2s);
  flow_kernel<<<dim3(B_N / 64), dim3(512), 0, stream>>>(z, b1, W1s, W2s, M, dz, tr);
}

// Round 5
// 296.772 us; speedup vs baseline: 1.4049x; 1.2897x over previous
//
#include <hip/hip_runtime.h>
#include <cstdint>
#include <cstddef>

// Problem constants
#define B_N 65536
#define D_N 256
#define W_N 1024

typedef __bf16 bf16x8 __attribute__((ext_vector_type(8)));
typedef float f32x4 __attribute__((ext_vector_type(4)));
typedef unsigned short u16x8 __attribute__((ext_vector_type(8)));

__device__ __forceinline__ unsigned short f2bf(float f) {
  // round-to-nearest-even f32 -> bf16
  unsigned u = __float_as_uint(f);
  u += 0x7fffu + ((u >> 16) & 1u);
  return (unsigned short)(u >> 16);
}

__device__ __forceinline__ unsigned short f2bf_rn(float f) {
  // round-to-nearest (ties away) -- 2 VALU ops, same 0.5 ULP max error
  return (unsigned short)((__float_as_uint(f) + 0x8000u) >> 16);
}

// LDS bank swizzle (verified r4: conflicts 3.9M -> 262k).  Pure function of the
// 16B-slot index; fragment reads sweep 64 consecutive slots (bijective, still
// conflict-free); staging/epilogue writes get spread over all 8 bank groups.
__device__ __forceinline__ int swz(int slot) {
  return slot ^ ((slot >> 4) & 7) ^ ((slot >> 8) & 7);
}

// ---------------------------------------------------------------------------
// Prep (r2-proven): cast W1 [1024x256], W2 [256x1024] to bf16 row-major;
// M[j] = sum_i W1[j,i]*W2[i,j].
// ---------------------------------------------------------------------------
__global__ __launch_bounds__(256) void prep_kernel(
    const float* __restrict__ W1, const float* __restrict__ W2,
    unsigned short* __restrict__ W1b, unsigned short* __restrict__ W2b,
    float* __restrict__ M) {
  const int j = blockIdx.x;    // 0..1023
  const int t = threadIdx.x;   // 0..255
  const int gid = j * 256 + t;
  float w1 = W1[gid];
  float w2g = W2[gid];
  W1b[gid] = f2bf(w1);
  W2b[gid] = f2bf(w2g);
  float p = w1 * W2[t * W_N + j];
  #pragma unroll
  for (int m = 32; m; m >>= 1) p += __shfl_xor(p, m);
  __shared__ float red[4];
  if ((t & 63) == 0) red[t >> 6] = p;
  __syncthreads();
  if (t == 0) M[j] = red[0] + red[1] + red[2] + red[3];
}

// ---------------------------------------------------------------------------
// Fused flow kernel.  BM=64 rows/block, 512 thr = 8 waves; wave tile 64x32
// (tn in {0,1}).  W chunked 4x256.  h DOUBLE-BUFFERED -> ONE barrier/chunk:
//   G1(0); E(0)->h[0]; barrier; { G2(c); G1(c+1); E(c+1)->h[(c+1)&1]; barrier }
// The barrier at end of chunk c guarantees h[c&1] is fully consumed before
// E(c+2) rewrites it, and h[(c+1)&1] is fully written before G2(c+1).
// LDS layouts (all verified): element (m,k) -> 16B slot
//   swz(((k/32)*4 + m/16)*64 + ((k%32)/8)*16 + (m%16)), ushort index k%8.
// MFMA 16x16x32 bf16: A[m=lane&15][k=(lane>>4)*8+i]; C row=(lane>>4)*4+r, col=lane&15.
// Weight B-frags read row-major from W1b/W2b (r2 addressing -- the r4 "line"
// layout caused a 4x HBM-traffic cache pathology; do not re-introduce).
// ---------------------------------------------------------------------------
__global__ __launch_bounds__(512, 2) void flow_kernel(
    const float* __restrict__ z, const float* __restrict__ b1,
    const unsigned short* __restrict__ W1b, const unsigned short* __restrict__ W2b,
    const float* __restrict__ M, float* __restrict__ dz, float* __restrict__ tr) {
  __shared__ __align__(16) unsigned short z_sh[64 * 256];     // 32 KB
  __shared__ __align__(16) unsigned short h_sh[2][64 * 256];  // 64 KB

  const int tid = threadIdx.x;
  const int wave = tid >> 6;   // 0..7
  const int lane = tid & 63;
  const int l15 = lane & 15;
  const int q = lane >> 4;     // quad 0..3
  const int row0 = blockIdx.x * 64;
  const int colw = wave * 32;  // wave's column strip within the 256-chunk

  // ---- stage z tile [64 x 256] f32 -> bf16 blocked+swizzled layout ----
  #pragma unroll
  for (int it = 0; it < 4; ++it) {
    int id = it * 512 + tid;
    int m = id >> 5;  // row 0..63
    int o = id & 31;  // octet of 8 floats
    const float* gp = z + (size_t)(row0 + m) * D_N + o * 8;
    f32x4 a = *(const f32x4*)gp;
    f32x4 b = *(const f32x4*)(gp + 4);
    u16x8 v;
    v[0] = f2bf_rn(a[0]); v[1] = f2bf_rn(a[1]); v[2] = f2bf_rn(a[2]); v[3] = f2bf_rn(a[3]);
    v[4] = f2bf_rn(b[0]); v[5] = f2bf_rn(b[1]); v[6] = f2bf_rn(b[2]); v[7] = f2bf_rn(b[3]);
    int slot = swz(((o >> 2) * 4 + (m >> 4)) * 64 + (o & 3) * 16 + (m & 15));
    *(u16x8*)(z_sh + slot * 8) = v;
  }
  __syncthreads();

  f32x4 acc2[4][2]; // dz accumulator: [tm][tn], cols = colw + tn*16 + l15
  #pragma unroll
  for (int a = 0; a < 4; ++a)
    #pragma unroll
    for (int b = 0; b < 2; ++b)
      acc2[a][b] = (f32x4){0.f, 0.f, 0.f, 0.f};
  float trp[4][4]; // trace partial per (tm, r): row = tm*16 + q*4 + r
  #pragma unroll
  for (int a = 0; a < 4; ++a)
    #pragma unroll
    for (int r = 0; r < 4; ++r) trp[a][r] = 0.f;

  f32x4 acc1[4][2];

  // ======== GEMM1 for a chunk (K=256 from z_sh) ========
  auto gemm1 = [&](int c) {
    const int j0 = c * 256;
    #pragma unroll
    for (int a = 0; a < 4; ++a)
      #pragma unroll
      for (int b = 0; b < 2; ++b)
        acc1[a][b] = (f32x4){0.f, 0.f, 0.f, 0.f};
    #pragma unroll
    for (int ks = 0; ks < 8; ++ks) {
      bf16x8 afr[4];
      #pragma unroll
      for (int tm = 0; tm < 4; ++tm)
        afr[tm] = *(const bf16x8*)(z_sh + swz((ks * 4 + tm) * 64 + lane) * 8);
      bf16x8 bfr[2];
      #pragma unroll
      for (int tn = 0; tn < 2; ++tn)
        bfr[tn] = *(const bf16x8*)(W1b +
            (size_t)(j0 + colw + tn * 16 + l15) * D_N + ks * 32 + q * 8);
      #pragma unroll
      for (int tm = 0; tm < 4; ++tm)
        #pragma unroll
        for (int tn = 0; tn < 2; ++tn)
          acc1[tm][tn] = __builtin_amdgcn_mfma_f32_16x16x32_bf16(
              afr[tm], bfr[tn], acc1[tm][tn], 0, 0, 0);
    }
  };

  // ======== epilogue for a chunk: softplus -> h_sh[buf], sigmoid*M -> trp ====
  auto epi = [&](int c) {
    const int j0 = c * 256;
    unsigned short* hb = h_sh[c & 1];
    #pragma unroll
    for (int tn = 0; tn < 2; ++tn) {
      const int jl = colw + tn * 16 + l15;
      const int jg = j0 + jl;
      const float b1v = b1[jg];
      const float Mv = M[jg];
      const int sbase = ((jl >> 5) * 4) * 64 + ((jl >> 3) & 3) * 16;
      const int elem_lo = (jl & 7);
      #pragma unroll
      for (int tm = 0; tm < 4; ++tm) {
        #pragma unroll
        for (int r = 0; r < 4; ++r) {
          float x = acc1[tm][tn][r] + b1v;
          float e = __expf(-fabsf(x));
          float inv = __builtin_amdgcn_rcpf(1.0f + e);
          float sig = (x >= 0.f) ? inv : (1.0f - inv);
          float sp = fmaxf(x, 0.f) + __logf(1.0f + e);
          trp[tm][r] += sig * Mv;
          int slot = swz(sbase + tm * 64 + (q * 4 + r));
          hb[slot * 8 + elem_lo] = f2bf_rn(sp);
        }
      }
    }
  };

  // ======== GEMM2 for a chunk (K=256 from h_sh[buf]) ========
  auto gemm2 = [&](int c) {
    const int j0 = c * 256;
    const unsigned short* hb = h_sh[c & 1];
    #pragma unroll
    for (int ks = 0; ks < 8; ++ks) {
      bf16x8 afr[4];
      #pragma unroll
      for (int tm = 0; tm < 4; ++tm)
        afr[tm] = *(const bf16x8*)(hb + swz((ks * 4 + tm) * 64 + lane) * 8);
      bf16x8 bfr[2];
      #pragma unroll
      for (int tn = 0; tn < 2; ++tn)
        bfr[tn] = *(const bf16x8*)(W2b +
            (size_t)(colw + tn * 16 + l15) * W_N + j0 + ks * 32 + q * 8);
      #pragma unroll
      for (int tm = 0; tm < 4; ++tm)
        #pragma unroll
        for (int tn = 0; tn < 2; ++tn)
          acc2[tm][tn] = __builtin_amdgcn_mfma_f32_16x16x32_bf16(
              afr[tm], bfr[tn], acc2[tm][tn], 0, 0, 0);
    }
  };

  // prologue: fill h[0]
  gemm1(0);
  epi(0);
  __syncthreads();

  #pragma unroll 1
  for (int c = 0; c < 4; ++c) {
    gemm2(c);
    if (c < 3) {
      gemm1(c + 1);
      epi(c + 1);
      __syncthreads();
    }
  }

  // ---- store dz ----
  #pragma unroll
  for (int tm = 0; tm < 4; ++tm)
    #pragma unroll
    for (int tn = 0; tn < 2; ++tn)
      #pragma unroll
      for (int r = 0; r < 4; ++r)
        dz[(size_t)(row0 + tm * 16 + q * 4 + r) * D_N + colw + tn * 16 + l15] =
            acc2[tm][tn][r];

  // ---- trace: reduce 16 lanes per quad, cross-wave via LDS (z_sh dead) ----
  float* tr_sh = (float*)z_sh;
  if (tid < 64) tr_sh[tid] = 0.f;
  __syncthreads();
  #pragma unroll
  for (int tm = 0; tm < 4; ++tm) {
    #pragma unroll
    for (int r = 0; r < 4; ++r) {
      float v = trp[tm][r];
      v += __shfl_xor(v, 1);
      v += __shfl_xor(v, 2);
      v += __shfl_xor(v, 4);
      v += __shfl_xor(v, 8);
      if (l15 == 0) atomicAdd(tr_sh + tm * 16 + q * 4 + r, v);
    }
  }
  __syncthreads();
  if (tid < 64) tr[row0 + tid] = -tr_sh[tid];
}

extern "C" void kernel_launch(void* const* d_in, const int* in_sizes, int n_in,
                              void* d_out, int out_size, void* d_ws, size_t ws_size,
                              hipStream_t stream) {
  (void)in_sizes; (void)n_in; (void)out_size; (void)ws_size;
  // inputs: t[1], z[B,D], W1[W,D], b1[W], W2[D,W]  (all f32)
  const float* z  = (const float*)d_in[1];
  const float* W1 = (const float*)d_in[2];
  const float* b1 = (const float*)d_in[3];
  const float* W2 = (const float*)d_in[4];
  float* dz = (float*)d_out;          // [B, D]
  float* tr = dz + (size_t)B_N * D_N; // [B]

  unsigned short* W1b = (unsigned short*)d_ws;   // 512 KB
  unsigned short* W2b = W1b + (size_t)W_N * D_N; // 512 KB
  float* M = (float*)(W2b + (size_t)W_N * D_N);  // 4 KB

  prep_kernel<<<dim3(W_N), dim3(256), 0, stream>>>(W1, W2, W1b, W2b, M);
  flow_kernel<<<dim3(B_N / 64), dim3(512), 0, stream>>>(z, b1, W1b, W2b, M, dz, tr);
}